// Round 6
// baseline (1562.700 us; speedup 1.0000x reference)
//
#include <hip/hip_runtime.h>
#include <math.h>

#define L_DIM 8
#define B_DIM 8
#define C_DIM 512
#define D_DIM 4096
#define NPAIR 64          // L*B
#define KSEL_CNT 52       // 52nd smallest = 0-based sorted index 51 (k = C/10)

typedef __attribute__((ext_vector_type(8))) _Float16 half8;  // MFMA f16 operand
typedef __attribute__((ext_vector_type(4))) float f32x4;     // MFMA acc

// chunk-index bank swizzle: XORs kc bits into bank bits. Reader quarters see a
// constant XOR (conflict-free contiguous 256B); writer 16-lane groups spread
// over 8 bank-quads at worst 2-way (free per m136). 0 conflicts measured (R5).
__device__ __forceinline__ int swz(int c) { return c ^ (((c >> 4) & 3) << 1); }

__device__ __forceinline__ uint4 cvth8(float4 f0, float4 f1) {
    half8 h;
    h[0] = (_Float16)f0.x; h[1] = (_Float16)f0.y;
    h[2] = (_Float16)f0.z; h[3] = (_Float16)f0.w;
    h[4] = (_Float16)f1.x; h[5] = (_Float16)f1.y;
    h[6] = (_Float16)f1.z; h[7] = (_Float16)f1.w;
    return __builtin_bit_cast(uint4, h);
}

// ---------------------------------------------------------------------------
// Kernel 1: G = F*F^T per (l,b) pair, fp16 MFMA, 256x256 tiles, full 2x2 grid
// per pair -> 4*np = 256 blocks (1/CU). 512 threads = 8 waves as 2x4; wave
// tile 128x64 -> acc[8][4] = 128 VGPR. __launch_bounds__(512,1): clang maps
// (B,minBlocks) -> waves/EU = B*minBlocks/256 = 2 -> VGPR cap 256 (R4's (512,2)
// gave cap 128 -> scratch spill; this is the fix).
// bid = tid*np + pl -> pair's 4 blocks share an XCD (np%8==0); per-slab pair
// working set 64 KB -> L2-shared, ~compulsory HBM fetch (R4: 316 MB).
// ---------------------------------------------------------------------------
__global__ __launch_bounds__(512, 1)
void gram_mfma(const float* __restrict__ F, float* __restrict__ G,
               float* __restrict__ diag, int pair0, int np) {
    __shared__ uint4 sA[1024], sB[1024];    // 32 KB

    const int bid = blockIdx.x;
    const int pl  = bid % np;       // chunk-local pair
    const int tid = bid / np;       // 0..3
    const int ti = tid >> 1, tj = tid & 1;
    const int p = pair0 + pl;

    const float* Fp = F + (size_t)p * C_DIM * D_DIM;
    float* Gp = G + (size_t)pl * C_DIM * C_DIM;

    const int t = threadIdx.x, lane = t & 63, w = t >> 6;   // 8 waves
    const int wr = w >> 2, wc = w & 3;                       // 2x4 wave grid

    // staging: thread t covers rows r0, r0+128 of both panels; k-chunk kc*8..+8
    const int r0 = t >> 2, kc = t & 3;
    const int cA  = (r0 >> 4) * 64 + (r0 & 15) + kc * 16;   // frag-linear chunk
    const int st0 = swz(cA), st1 = swz(cA + 512);

    const float* aP = Fp + (size_t)(ti * 256 + r0) * D_DIM + kc * 8;
    const float* bP = Fp + (size_t)(tj * 256 + r0) * D_DIM + kc * 8;
    const size_t rowHop = (size_t)128 * D_DIM;

    f32x4 acc[8][4];
#pragma unroll
    for (int m = 0; m < 8; ++m)
#pragma unroll
        for (int n = 0; n < 4; ++n) acc[m][n] = (f32x4){0.f, 0.f, 0.f, 0.f};

    // frag read addresses (loop-invariant)
    int rdA[8], rdB[4];
#pragma unroll
    for (int m = 0; m < 8; ++m) rdA[m] = swz((wr * 8 + m) * 64 + lane);
#pragma unroll
    for (int n = 0; n < 4; ++n) rdB[n] = swz((wc * 4 + n) * 64 + lane);

    // prologue: load slab 0
    float4 fA0 = *(const float4*)(aP),          fA1 = *(const float4*)(aP + 4);
    float4 fA2 = *(const float4*)(aP + rowHop), fA3 = *(const float4*)(aP + rowHop + 4);
    float4 fB0 = *(const float4*)(bP),          fB1 = *(const float4*)(bP + 4);
    float4 fB2 = *(const float4*)(bP + rowHop), fB3 = *(const float4*)(bP + rowHop + 4);

    for (int k0 = 0; k0 < D_DIM; k0 += 32) {
        const uint4 uA0 = cvth8(fA0, fA1), uA1 = cvth8(fA2, fA3);
        const uint4 uB0 = cvth8(fB0, fB1), uB1 = cvth8(fB2, fB3);
        __syncthreads();          // prior slab's frag reads consumed
        sA[st0] = uA0; sA[st1] = uA1;
        sB[st0] = uB0; sB[st1] = uB1;

        if (k0 + 32 < D_DIM) {    // issue next-slab loads; land during MFMA
            const float* ap = aP + k0 + 32;
            const float* bp = bP + k0 + 32;
            fA0 = *(const float4*)(ap);          fA1 = *(const float4*)(ap + 4);
            fA2 = *(const float4*)(ap + rowHop); fA3 = *(const float4*)(ap + rowHop + 4);
            fB0 = *(const float4*)(bp);          fB1 = *(const float4*)(bp + 4);
            fB2 = *(const float4*)(bp + rowHop); fB3 = *(const float4*)(bp + rowHop + 4);
        }
        __builtin_amdgcn_sched_barrier(0);   // don't sink the loads past MFMA
        __syncthreads();

        half8 ah[8], bh[4];
#pragma unroll
        for (int n = 0; n < 4; ++n) bh[n] = __builtin_bit_cast(half8, sB[rdB[n]]);
#pragma unroll
        for (int m = 0; m < 8; ++m) ah[m] = __builtin_bit_cast(half8, sA[rdA[m]]);
#pragma unroll
        for (int m = 0; m < 8; ++m)
#pragma unroll
            for (int n = 0; n < 4; ++n)
                acc[m][n] = __builtin_amdgcn_mfma_f32_16x16x32_f16(ah[m], bh[n], acc[m][n], 0, 0, 0);
    }

    // epilogue: C/D map col=lane&15, row=(lane>>4)*4+reg
    const int fr = (lane >> 4) * 4, fc = lane & 15;
#pragma unroll
    for (int m = 0; m < 8; ++m) {
        const int row = ti * 256 + wr * 128 + m * 16 + fr;
#pragma unroll
        for (int n = 0; n < 4; ++n) {
            const int col = tj * 256 + wc * 64 + n * 16 + fc;
#pragma unroll
            for (int j = 0; j < 4; ++j)
                Gp[(size_t)(row + j) * C_DIM + col] = acc[m][n][j];
        }
    }
    // diag: tiles ti==tj; global row==col needs fr+j==fc (lane cond) and
    // n = 8*wr + m - 4*wc in [0,4).
    if (ti == tj && ((fc >> 2) == (lane >> 4))) {
        const int j = lane & 3;
#pragma unroll
        for (int m = 0; m < 8; ++m) {
            const int n = 8 * wr + m - 4 * wc;
            if (n >= 0 && n < 4)
                diag[(size_t)p * C_DIM + ti * 256 + wr * 128 + m * 16 + fc] = acc[m][n][j];
        }
    }
}

// ---------------------------------------------------------------------------
// Kernel 2: one wave per row. d2[m] = sq[n]+sq[m]-2G[n,m] in 8 regs/lane;
// bit-pattern bisection -> exact 52nd smallest (attained value).
// ---------------------------------------------------------------------------
__global__ __launch_bounds__(256)
void select_kernel(const float* __restrict__ G, const float* __restrict__ diag,
                   float* __restrict__ kth, int pair0) {
    const int w = threadIdx.x >> 6, lane = threadIdx.x & 63;
    const int row = blockIdx.x * 4 + w;
    const int pl  = blockIdx.y;
    const int p   = pair0 + pl;

    const float* Grow = G + ((size_t)pl * C_DIM + row) * C_DIM;
    const float* dg   = diag + (size_t)p * C_DIM;
    const float  sqn  = dg[row];

    const float4 g0 = *(const float4*)(Grow + lane * 8);
    const float4 g1 = *(const float4*)(Grow + lane * 8 + 4);
    const float4 d0 = *(const float4*)(dg + lane * 8);
    const float4 d1 = *(const float4*)(dg + lane * 8 + 4);

    float v[8];
    v[0] = fmaxf(sqn + d0.x - 2.f * g0.x, 0.f);
    v[1] = fmaxf(sqn + d0.y - 2.f * g0.y, 0.f);
    v[2] = fmaxf(sqn + d0.z - 2.f * g0.z, 0.f);
    v[3] = fmaxf(sqn + d0.w - 2.f * g0.w, 0.f);
    v[4] = fmaxf(sqn + d1.x - 2.f * g1.x, 0.f);
    v[5] = fmaxf(sqn + d1.y - 2.f * g1.y, 0.f);
    v[6] = fmaxf(sqn + d1.z - 2.f * g1.z, 0.f);
    v[7] = fmaxf(sqn + d1.w - 2.f * g1.w, 0.f);

    unsigned lo = 0u, hi = 0x47800000u;   // 65536.0f >> max d2 (~9e3)
    while (lo < hi) {
        const unsigned mid = (lo + hi) >> 1;
        const float piv = __uint_as_float(mid);
        int c = 0;
#pragma unroll
        for (int i = 0; i < 8; ++i) c += (v[i] <= piv) ? 1 : 0;
#pragma unroll
        for (int off = 32; off > 0; off >>= 1) c += __shfl_xor(c, off);
        if (c >= KSEL_CNT) hi = mid; else lo = mid + 1;
    }
    if (lane == 0)
        kth[(size_t)p * C_DIM + row] = sqrtf(fmaxf(__uint_as_float(lo), 1e-12f));
}

// ---------------------------------------------------------------------------
// Kernel 3: per-layer fp64 fixed-order sum of 4096 kth-distances.
// ---------------------------------------------------------------------------
__global__ __launch_bounds__(256)
void reduce_kernel(const float* __restrict__ kth, double* __restrict__ hsum) {
    __shared__ double sd[256];
    const int l = blockIdx.x;
    const float* base = kth + (size_t)l * B_DIM * C_DIM;
    double acc = 0.0;
    for (int i = threadIdx.x; i < B_DIM * C_DIM; i += 256)
        acc += (double)base[i];
    sd[threadIdx.x] = acc;
    __syncthreads();
    for (int sstep = 128; sstep > 0; sstep >>= 1) {
        if (threadIdx.x < sstep) sd[threadIdx.x] += sd[threadIdx.x + sstep];
        __syncthreads();
    }
    if (threadIdx.x == 0) hsum[l] = sd[0];
}

// ---------------------------------------------------------------------------
// Kernel 4: ents = log(S+1); var(d1,ddof=1)+var(d2,ddof=1).
// ---------------------------------------------------------------------------
__global__ void final_kernel(const double* __restrict__ hsum, float* __restrict__ out) {
    double ents[L_DIM];
    for (int l = 0; l < L_DIM; ++l) ents[l] = log(hsum[l] + 1.0);
    const double d1[2] = { ents[2] - ents[1], ents[3] - ents[2] };
    const double d2[4] = { ents[4] - ents[3], ents[5] - ents[4],
                           ents[6] - ents[5], ents[7] - ents[6] };
    const double m1 = (d1[0] + d1[1]) * 0.5;
    const double v1 = (d1[0] - m1) * (d1[0] - m1) + (d1[1] - m1) * (d1[1] - m1);
    double m2 = 0.0;
    for (int i = 0; i < 4; ++i) m2 += d2[i];
    m2 *= 0.25;
    double v2 = 0.0;
    for (int i = 0; i < 4; ++i) v2 += (d2[i] - m2) * (d2[i] - m2);
    v2 /= 3.0;
    out[0] = (float)(v1 + v2);
}

// ---------------------------------------------------------------------------
extern "C" void kernel_launch(void* const* d_in, const int* in_sizes, int n_in,
                              void* d_out, int out_size, void* d_ws, size_t ws_size,
                              hipStream_t stream) {
    const float* net = (const float*)d_in[0];
    float* out = (float*)d_out;
    char* ws = (char*)d_ws;

    double* hsum = (double*)ws;
    float*  diag = (float*)(ws + 4096);
    float*  kth  = (float*)(ws + 4096 + 131072);
    const size_t gOff = 4096 + 2 * 131072;
    float*  G    = (float*)(ws + gOff);

    const size_t perPair = (size_t)C_DIM * C_DIM * sizeof(float);
    const size_t avail = ws_size > gOff ? ws_size - gOff : 0;
    int chunk = (int)(avail / perPair);
    if (chunk > NPAIR) chunk = NPAIR;
    if (chunk < 1) chunk = 1;

    for (int p0 = 0; p0 < NPAIR; p0 += chunk) {
        const int np = (NPAIR - p0) < chunk ? (NPAIR - p0) : chunk;
        gram_mfma<<<dim3(4 * np), dim3(512), 0, stream>>>(net, G, diag, p0, np);
        select_kernel<<<dim3(C_DIM / 4, np), dim3(256), 0, stream>>>(G, diag, kth, p0);
    }
    reduce_kernel<<<dim3(L_DIM), dim3(256), 0, stream>>>(kth, hsum);
    final_kernel<<<dim3(1), dim3(1), 0, stream>>>(hsum, out);
}

// Round 7
// 385.950 us; speedup vs baseline: 4.0490x; 4.0490x over previous
//
#include <hip/hip_runtime.h>
#include <math.h>

#define L_DIM 8
#define B_DIM 8
#define C_DIM 512
#define D_DIM 4096
#define NPAIR 64          // L*B
#define KSEL_CNT 52       // 52nd smallest = 0-based sorted index 51 (k = C/10)
#define NSLAB 128         // D_DIM / 32

typedef __attribute__((ext_vector_type(8))) _Float16 half8;  // MFMA f16 operand
typedef __attribute__((ext_vector_type(4))) float f32x4;     // MFMA acc

// chunk-index bank swizzle (proven 0 conflicts in R5/R6 counters)
__device__ __forceinline__ int swz(int c) { return c ^ (((c >> 4) & 3) << 1); }

__device__ __forceinline__ uint4 cvth8(float4 f0, float4 f1) {
    half8 h;
    h[0] = (_Float16)f0.x; h[1] = (_Float16)f0.y;
    h[2] = (_Float16)f0.z; h[3] = (_Float16)f0.w;
    h[4] = (_Float16)f1.x; h[5] = (_Float16)f1.y;
    h[6] = (_Float16)f1.z; h[7] = (_Float16)f1.w;
    return __builtin_bit_cast(uint4, h);
}

// ---------------------------------------------------------------------------
// Kernel 1: G = F*F^T per (l,b) pair, fp16 MFMA. Tile 256(M)x128(N), 8 blocks
// per pair (2x4 grid), 512 threads = 8 waves (4x2), wave tile 64x64,
// acc[4][4] = 64 VGPR (the no-spill ceiling established by R3/R5; R4/R6's
// 128-reg acc spilled regardless of launch bounds).
// K-loop is the minimum 2-phase pipeline: double-buffered LDS, ONE
// __syncthreads per slab, global loads issued AFTER the barrier so the
// barrier's implicit vmcnt(0) drain (R3-R6's structural bug) can't kill the
// prefetch; loads land under the MFMA cluster, waited only at next cvt.
// bid = tile*np + pl -> pair's 8 blocks share an XCD when np%8==0.
// ---------------------------------------------------------------------------
__global__ __launch_bounds__(512)
void gram_mfma(const float* __restrict__ F, float* __restrict__ G,
               float* __restrict__ diag, int pair0, int np) {
    __shared__ uint4 sA[2][1024], sB[2][512];    // 48 KB (2 blocks/CU -> 96 KB)

    const int bid = blockIdx.x;
    const int pl  = bid % np;       // chunk-local pair
    const int tid = bid / np;       // 0..7
    const int ti = tid >> 2, tj = tid & 3;   // 2 row-tiles x 4 col-tiles
    const int p = pair0 + pl;

    const float* Fp = F + (size_t)p * C_DIM * D_DIM;
    float* Gp = G + (size_t)pl * C_DIM * C_DIM;

    const int t = threadIdx.x, lane = t & 63, w = t >> 6;   // 8 waves
    const int wr = w >> 1, wc = w & 1;                       // 4x2 wave grid

    // staging: thread t covers A rows r0, r0+128 and B row r0; k-chunk kc*8..+8
    const int r0 = t >> 2, kc = t & 3;
    const int cA  = (r0 >> 4) * 64 + (r0 & 15) + kc * 16;   // frag-linear chunk
    const int st0 = swz(cA), st1 = swz(cA + 512);

    const float* aP = Fp + (size_t)(ti * 256 + r0) * D_DIM + kc * 8;
    const float* bP = Fp + (size_t)(tj * 128 + r0) * D_DIM + kc * 8;
    const size_t rowHop = (size_t)128 * D_DIM;

    f32x4 acc[4][4];
#pragma unroll
    for (int m = 0; m < 4; ++m)
#pragma unroll
        for (int n = 0; n < 4; ++n) acc[m][n] = (f32x4){0.f, 0.f, 0.f, 0.f};

    // frag read addresses (loop-invariant)
    int rdA[4], rdB[4];
#pragma unroll
    for (int m = 0; m < 4; ++m) rdA[m] = swz((wr * 4 + m) * 64 + lane);
#pragma unroll
    for (int n = 0; n < 4; ++n) rdB[n] = swz((wc * 4 + n) * 64 + lane);

    // prologue: load slab 0 into regs
    float4 fA0 = *(const float4*)(aP),          fA1 = *(const float4*)(aP + 4);
    float4 fA2 = *(const float4*)(aP + rowHop), fA3 = *(const float4*)(aP + rowHop + 4);
    float4 fB0 = *(const float4*)(bP),          fB1 = *(const float4*)(bP + 4);

    for (int s = 0; s < NSLAB; ++s) {
        const int buf = s & 1;
        // phase 1: convert prev-issued loads (vmcnt wait happens here) + stage
        sA[buf][st0] = cvth8(fA0, fA1);
        sA[buf][st1] = cvth8(fA2, fA3);
        sB[buf][st0] = cvth8(fB0, fB1);
        __syncthreads();   // the ONLY barrier; next-slab loads not yet issued

        // phase 2: issue next-slab loads -- they fly across the MFMA cluster
        if (s + 1 < NSLAB) {
            const float* ap = aP + (s + 1) * 32;
            const float* bp = bP + (s + 1) * 32;
            fA0 = *(const float4*)(ap);          fA1 = *(const float4*)(ap + 4);
            fA2 = *(const float4*)(ap + rowHop); fA3 = *(const float4*)(ap + rowHop + 4);
            fB0 = *(const float4*)(bp);          fB1 = *(const float4*)(bp + 4);
        }

        half8 ah[4], bh[4];
#pragma unroll
        for (int m = 0; m < 4; ++m) ah[m] = __builtin_bit_cast(half8, sA[buf][rdA[m]]);
#pragma unroll
        for (int n = 0; n < 4; ++n) bh[n] = __builtin_bit_cast(half8, sB[buf][rdB[n]]);
#pragma unroll
        for (int m = 0; m < 4; ++m)
#pragma unroll
            for (int n = 0; n < 4; ++n)
                acc[m][n] = __builtin_amdgcn_mfma_f32_16x16x32_f16(ah[m], bh[n], acc[m][n], 0, 0, 0);
        // no second barrier: iter s+1 writes buf^1, whose last readers were
        // iter s-1, separated by this iter's barrier.
    }

    // epilogue: C/D map col=lane&15, row=(lane>>4)*4+reg
    const int fr = (lane >> 4) * 4, fc = lane & 15;
#pragma unroll
    for (int m = 0; m < 4; ++m) {
        const int row = ti * 256 + wr * 64 + m * 16 + fr;
#pragma unroll
        for (int n = 0; n < 4; ++n) {
            const int col = tj * 128 + wc * 64 + n * 16 + fc;
#pragma unroll
            for (int j = 0; j < 4; ++j)
                Gp[(size_t)(row + j) * C_DIM + col] = acc[m][n][j];
        }
    }
    // diag (verified in R5, absmax 0): tile overlaps diagonal iff tj>>1 == ti;
    // local row==col needs wr == wc + 2*(tj&1), m==n, fr+j==fc.
    if ((tj >> 1) == ti && wr == wc + 2 * (tj & 1) && ((fc >> 2) == (lane >> 4))) {
        const int j = lane & 3;
#pragma unroll
        for (int m = 0; m < 4; ++m)
            diag[(size_t)p * C_DIM + ti * 256 + wr * 64 + m * 16 + fc] = acc[m][m][j];
    }
}

// ---------------------------------------------------------------------------
// Kernel 2: one wave per row. d2[m] = sq[n]+sq[m]-2G[n,m] in 8 regs/lane;
// bit-pattern bisection -> exact 52nd smallest (attained value).
// ---------------------------------------------------------------------------
__global__ __launch_bounds__(256)
void select_kernel(const float* __restrict__ G, const float* __restrict__ diag,
                   float* __restrict__ kth, int pair0) {
    const int w = threadIdx.x >> 6, lane = threadIdx.x & 63;
    const int row = blockIdx.x * 4 + w;
    const int pl  = blockIdx.y;
    const int p   = pair0 + pl;

    const float* Grow = G + ((size_t)pl * C_DIM + row) * C_DIM;
    const float* dg   = diag + (size_t)p * C_DIM;
    const float  sqn  = dg[row];

    const float4 g0 = *(const float4*)(Grow + lane * 8);
    const float4 g1 = *(const float4*)(Grow + lane * 8 + 4);
    const float4 d0 = *(const float4*)(dg + lane * 8);
    const float4 d1 = *(const float4*)(dg + lane * 8 + 4);

    float v[8];
    v[0] = fmaxf(sqn + d0.x - 2.f * g0.x, 0.f);
    v[1] = fmaxf(sqn + d0.y - 2.f * g0.y, 0.f);
    v[2] = fmaxf(sqn + d0.z - 2.f * g0.z, 0.f);
    v[3] = fmaxf(sqn + d0.w - 2.f * g0.w, 0.f);
    v[4] = fmaxf(sqn + d1.x - 2.f * g1.x, 0.f);
    v[5] = fmaxf(sqn + d1.y - 2.f * g1.y, 0.f);
    v[6] = fmaxf(sqn + d1.z - 2.f * g1.z, 0.f);
    v[7] = fmaxf(sqn + d1.w - 2.f * g1.w, 0.f);

    unsigned lo = 0u, hi = 0x47800000u;   // 65536.0f >> max d2 (~9e3)
    while (lo < hi) {
        const unsigned mid = (lo + hi) >> 1;
        const float piv = __uint_as_float(mid);
        int c = 0;
#pragma unroll
        for (int i = 0; i < 8; ++i) c += (v[i] <= piv) ? 1 : 0;
#pragma unroll
        for (int off = 32; off > 0; off >>= 1) c += __shfl_xor(c, off);
        if (c >= KSEL_CNT) hi = mid; else lo = mid + 1;
    }
    if (lane == 0)
        kth[(size_t)p * C_DIM + row] = sqrtf(fmaxf(__uint_as_float(lo), 1e-12f));
}

// ---------------------------------------------------------------------------
// Kernel 3: per-layer fp64 fixed-order sum of 4096 kth-distances.
// ---------------------------------------------------------------------------
__global__ __launch_bounds__(256)
void reduce_kernel(const float* __restrict__ kth, double* __restrict__ hsum) {
    __shared__ double sd[256];
    const int l = blockIdx.x;
    const float* base = kth + (size_t)l * B_DIM * C_DIM;
    double acc = 0.0;
    for (int i = threadIdx.x; i < B_DIM * C_DIM; i += 256)
        acc += (double)base[i];
    sd[threadIdx.x] = acc;
    __syncthreads();
    for (int sstep = 128; sstep > 0; sstep >>= 1) {
        if (threadIdx.x < sstep) sd[threadIdx.x] += sd[threadIdx.x + sstep];
        __syncthreads();
    }
    if (threadIdx.x == 0) hsum[l] = sd[0];
}

// ---------------------------------------------------------------------------
// Kernel 4: ents = log(S+1); var(d1,ddof=1)+var(d2,ddof=1).
// ---------------------------------------------------------------------------
__global__ void final_kernel(const double* __restrict__ hsum, float* __restrict__ out) {
    double ents[L_DIM];
    for (int l = 0; l < L_DIM; ++l) ents[l] = log(hsum[l] + 1.0);
    const double d1[2] = { ents[2] - ents[1], ents[3] - ents[2] };
    const double d2[4] = { ents[4] - ents[3], ents[5] - ents[4],
                           ents[6] - ents[5], ents[7] - ents[6] };
    const double m1 = (d1[0] + d1[1]) * 0.5;
    const double v1 = (d1[0] - m1) * (d1[0] - m1) + (d1[1] - m1) * (d1[1] - m1);
    double m2 = 0.0;
    for (int i = 0; i < 4; ++i) m2 += d2[i];
    m2 *= 0.25;
    double v2 = 0.0;
    for (int i = 0; i < 4; ++i) v2 += (d2[i] - m2) * (d2[i] - m2);
    v2 /= 3.0;
    out[0] = (float)(v1 + v2);
}

// ---------------------------------------------------------------------------
extern "C" void kernel_launch(void* const* d_in, const int* in_sizes, int n_in,
                              void* d_out, int out_size, void* d_ws, size_t ws_size,
                              hipStream_t stream) {
    const float* net = (const float*)d_in[0];
    float* out = (float*)d_out;
    char* ws = (char*)d_ws;

    double* hsum = (double*)ws;
    float*  diag = (float*)(ws + 4096);
    float*  kth  = (float*)(ws + 4096 + 131072);
    const size_t gOff = 4096 + 2 * 131072;
    float*  G    = (float*)(ws + gOff);

    const size_t perPair = (size_t)C_DIM * C_DIM * sizeof(float);
    const size_t avail = ws_size > gOff ? ws_size - gOff : 0;
    int chunk = (int)(avail / perPair);
    if (chunk > NPAIR) chunk = NPAIR;
    if (chunk < 1) chunk = 1;

    for (int p0 = 0; p0 < NPAIR; p0 += chunk) {
        const int np = (NPAIR - p0) < chunk ? (NPAIR - p0) : chunk;
        gram_mfma<<<dim3(8 * np), dim3(512), 0, stream>>>(net, G, diag, p0, np);
        select_kernel<<<dim3(C_DIM / 4, np), dim3(256), 0, stream>>>(G, diag, kth, p0);
    }
    reduce_kernel<<<dim3(L_DIM), dim3(256), 0, stream>>>(kth, hsum);
    final_kernel<<<dim3(1), dim3(1), 0, stream>>>(hsum, out);
}